// Round 2
// baseline (715.241 us; speedup 1.0000x reference)
//
#include <hip/hip_runtime.h>

// DockBoardAttention: B=65536, NDOCK=3, DCELL=25, C=32, HW=64, HD=16
// One wave64 per batch, lane = spatial position. No barriers; all LDS wave-private.
//
// Algebra: sc[n][s] = sum_c A[n][c] g[c][s],  A = k*(dock@Wq^T + bq)@Wk  (q.bk cancels in softmax)
//          out[n][e] = (sum_c U[e][c] z'[n][c]) / D[n] + c0[e]
//          z'[n][c] = sum_s e[n][s] g[c][s],  e = exp2(sc) (no max-sub: |sc| <~ 2),  D[n] = sum_s e[n][s]
//          U = Wo@Wv, c0 = Wo@bv + bo  (uses sum_s attn = 1)
// k = 0.25 * log2(e) folded into A so exp2 is used directly.
//
// g staging: 8 x global_load_lds dwordx4 (1 KB each). LDS dest is linear (HW: base+lane*16);
// the XOR swizzle lives in the per-lane GLOBAL source address (m173 pattern):
//   granule (c, s4) -> LDS slot 16*c + (s4 ^ (c&15))
//   scores read:  word = 64*c + (lane ^ (4*(c&15)))          (2-way, free)
//   z row read:   float4 at word 64*c + 4*(j ^ (c&15))       (rows spread over bank-groups)

#define NW 4

// ws layout (floats): M[25*32] @0, bkt[32] @800, U[16*32] @832, c0[16] @1344
__global__ void precompute_kernel(const float* __restrict__ Wq, const float* __restrict__ bq,
                                  const float* __restrict__ Wk, const float* __restrict__ Wv,
                                  const float* __restrict__ bv, const float* __restrict__ Wo,
                                  const float* __restrict__ bo, float* __restrict__ ws)
{
    const float K = 0.25f * 1.44269504088896f;
    const int t = threadIdx.x;
    for (int i = t; i < 800; i += 256) {           // M~[j][c] = K * sum_d Wq[d][j]*Wk[d][c]
        int j = i >> 5, c = i & 31;
        float s = 0.f;
        #pragma unroll
        for (int d = 0; d < 16; ++d) s += Wq[d * 25 + j] * Wk[d * 32 + c];
        ws[i] = s * K;
    }
    if (t < 32) {                                   // bkt~[c] = K * sum_d bq[d]*Wk[d][c]
        float s = 0.f;
        #pragma unroll
        for (int d = 0; d < 16; ++d) s += bq[d] * Wk[d * 32 + t];
        ws[800 + t] = s * K;
    }
    for (int i = t; i < 512; i += 256) {            // U[e][c] = sum_d Wo[e][d]*Wv[d][c]
        int e = i >> 5, c = i & 31;
        float s = 0.f;
        #pragma unroll
        for (int d = 0; d < 16; ++d) s += Wo[e * 16 + d] * Wv[d * 32 + c];
        ws[832 + i] = s;
    }
    if (t < 16) {                                   // c0[e] = sum_d Wo[e][d]*bv[d] + bo[e]
        float s = bo[t];
        #pragma unroll
        for (int d = 0; d < 16; ++d) s += Wo[t * 16 + d] * bv[d];
        ws[1344 + t] = s;
    }
}

__device__ __forceinline__ float rl(float v, int srclane) {
    return __int_as_float(__builtin_amdgcn_readlane(__float_as_int(v), srclane));
}

__device__ __forceinline__ void gload_lds16(const float* src, float* dst_lds) {
    __builtin_amdgcn_global_load_lds(
        (const __attribute__((address_space(1))) void*)src,
        (__attribute__((address_space(3))) void*)dst_lds, 16, 0, 0);
}

__global__ __launch_bounds__(256, 4) void dock_attn_kernel(
    const float* __restrict__ dock,   // [B,3,25]
    const float* __restrict__ grid,   // [B,32,64]
    const float* __restrict__ ws,     // precomputed M,bkt,U,c0
    float* __restrict__ out,          // [B,48]
    int b_total)
{
    __shared__ __align__(16) float gT[NW][2048];     // swizzled g[c][s], 8 KB/wave
    __shared__ __align__(16) float AL[NW][96];       // A[n][c], n-major
    __shared__ __align__(16) float attnL[NW][192];   // unnormalized e[n][s]
    __shared__ __align__(16) float zL[NW][104];      // z'[0..95], D[96..98]

    const int tid = threadIdx.x;
    const int w = tid >> 6, lane = tid & 63;
    const int b = blockIdx.x * NW + w;
    if (b >= b_total) return;          // never taken (B%4==0); no barriers so safe

    const float* Mg  = ws;
    const float* bkt = ws + 800;
    const float* Ug  = ws + 832;
    const float* c0  = ws + 1344;

    // ---- register loads FIRST: vmcnt is in-order, so anything issued after the
    //      8 KB g-DMA would stall the A-phase behind the whole stream ----
    float mreg[25];
    float bi = 0.f;
    if (lane < 32) {
        #pragma unroll
        for (int j = 0; j < 25; ++j) mreg[j] = Mg[j * 32 + lane];   // L1-hot
        bi = bkt[lane];
    }
    float d0 = dock[(size_t)b * 75 + lane];                    // dock idx 0..63
    float d1 = (lane < 11) ? dock[(size_t)b * 75 + 64 + lane] : 0.f;  // idx 64..74

    asm volatile("" ::: "memory");   // pin issue order: reg loads before the DMA stream

    // ---- async g stage: 8 x 1KB global->LDS; swizzle via per-lane global src addr ----
    {
        const float* gb = grid + (size_t)b * 2048;
        const int h = lane >> 4, q = lane & 15;
        #pragma unroll
        for (int i = 0; i < 8; ++i) {
            const int c = 4 * i + h;               // this lane's source row
            const int s4 = q ^ (c & 15);           // swizzled granule
            gload_lds16(gb + c * 64 + 4 * s4, &gT[w][i * 256]);   // dest base wave-uniform
        }
    }

    // ---- A[n][c] on lanes 0..31 (c = lane); overlaps the g stream (only waits d0/d1) ----
    if (lane < 32) {
        float a0 = bi, a1 = bi, a2 = bi;
        #pragma unroll
        for (int j = 0; j < 25; ++j) {
            float m = mreg[j];
            float q0 = rl(d0, j);
            float q1 = rl(d0, 25 + j);
            float q2 = (50 + j < 64) ? rl(d0, 50 + j) : rl(d1, 50 + j - 64);
            a0 = fmaf(q0, m, a0);
            a1 = fmaf(q1, m, a1);
            a2 = fmaf(q2, m, a2);
        }
        AL[w][lane] = a0; AL[w][32 + lane] = a1; AL[w][64 + lane] = a2;
    }

    asm volatile("s_waitcnt vmcnt(0)" ::: "memory");   // g tile resident in LDS

    // ---- scores: sc[n] = sum_c A[n][c]*g[c][lane]  (A via broadcast float4; g swizzled b32) ----
    float sc0 = 0.f, sc1 = 0.f, sc2 = 0.f;
    {
        const float* gTw = &gT[w][0];
        const float4* A4 = (const float4*)&AL[w][0];
        #pragma unroll
        for (int qq = 0; qq < 8; ++qq) {
            float4 a = A4[qq], bb = A4[8 + qq], cc = A4[16 + qq];
            const int c = 4 * qq;
            float g0 = gTw[((c + 0) << 6) + (lane ^ (((c + 0) & 15) << 2))];
            float g1 = gTw[((c + 1) << 6) + (lane ^ (((c + 1) & 15) << 2))];
            float g2 = gTw[((c + 2) << 6) + (lane ^ (((c + 2) & 15) << 2))];
            float g3 = gTw[((c + 3) << 6) + (lane ^ (((c + 3) & 15) << 2))];
            sc0 = fmaf(a.x, g0, fmaf(a.y, g1, fmaf(a.z, g2, fmaf(a.w, g3, sc0))));
            sc1 = fmaf(bb.x, g0, fmaf(bb.y, g1, fmaf(bb.z, g2, fmaf(bb.w, g3, sc1))));
            sc2 = fmaf(cc.x, g0, fmaf(cc.y, g1, fmaf(cc.z, g2, fmaf(cc.w, g3, sc2))));
        }
    }

    // ---- unnormalized numerators: |sc| <~ 2 (sigma~0.3, 5.5-sigma tail) -> no max-sub,
    //      no sum tree; 1/D is applied in the epilogue ----
    attnL[w][lane]       = exp2f(sc0);
    attnL[w][64 + lane]  = exp2f(sc1);
    attnL[w][128 + lane] = exp2f(sc2);

    // ---- z'[n][c] = sum_s e[n][s]*g[c][s]: pass 1, n = lane>>5, c = lane&31 ----
    {
        const int n = lane >> 5, c = lane & 31, cx = c & 15;
        const float4* ar = (const float4*)&attnL[w][n * 64];
        const float* grow = &gT[w][c << 6];
        float ax = 0.f, ay = 0.f, az = 0.f, aw = 0.f;
        #pragma unroll
        for (int j = 0; j < 16; ++j) {
            float4 a  = ar[j];
            float4 gg = *(const float4*)&grow[(j ^ cx) << 2];
            ax = fmaf(a.x, gg.x, ax);
            ay = fmaf(a.y, gg.y, ay);
            az = fmaf(a.z, gg.z, az);
            aw = fmaf(a.w, gg.w, aw);
        }
        zL[w][n * 32 + c] = (ax + ay) + (az + aw);
    }
    // ---- pass 2: lanes 0..31 -> n = 2; lanes 32..34 -> D[n] (softmax denominators) ----
    if (lane < 32) {
        const int cx = lane & 15;
        const float4* ar = (const float4*)&attnL[w][128];
        const float* grow = &gT[w][lane << 6];
        float ax = 0.f, ay = 0.f, az = 0.f, aw = 0.f;
        #pragma unroll
        for (int j = 0; j < 16; ++j) {
            float4 a  = ar[j];
            float4 gg = *(const float4*)&grow[(j ^ cx) << 2];
            ax = fmaf(a.x, gg.x, ax);
            ay = fmaf(a.y, gg.y, ay);
            az = fmaf(a.z, gg.z, az);
            aw = fmaf(a.w, gg.w, aw);
        }
        zL[w][64 + lane] = (ax + ay) + (az + aw);
    } else if (lane < 35) {
        const float4* ar = (const float4*)&attnL[w][(lane - 32) * 64];
        float s0 = 0.f, s1 = 0.f, s2 = 0.f, s3 = 0.f;
        #pragma unroll
        for (int j = 0; j < 16; ++j) {
            float4 a = ar[j];
            s0 += a.x; s1 += a.y; s2 += a.z; s3 += a.w;
        }
        zL[w][96 + (lane - 32)] = (s0 + s1) + (s2 + s3);
    }

    // ---- out[n][e] = (sum_c U[e][c]*z'[n][c]) * (1/D[n]) + c0[e]  (lanes 0..47) ----
    if (lane < 48) {
        const int n = lane >> 4, e = lane & 15;
        const float4* Ur = (const float4*)(Ug + e * 32);
        const float4* zr = (const float4*)&zL[w][n * 32];
        float dinv = __builtin_amdgcn_rcpf(zL[w][96 + n]);
        float acc0 = 0.f, acc1 = 0.f, acc2 = 0.f, acc3 = 0.f;
        #pragma unroll
        for (int qq = 0; qq < 8; ++qq) {
            float4 u = Ur[qq], z = zr[qq];
            acc0 = fmaf(u.x, z.x, acc0);
            acc1 = fmaf(u.y, z.y, acc1);
            acc2 = fmaf(u.z, z.z, acc2);
            acc3 = fmaf(u.w, z.w, acc3);
        }
        out[(size_t)b * 48 + lane] = fmaf((acc0 + acc1) + (acc2 + acc3), dinv, c0[e]);
    }
}

extern "C" void kernel_launch(void* const* d_in, const int* in_sizes, int n_in,
                              void* d_out, int out_size, void* d_ws, size_t ws_size,
                              hipStream_t stream) {
    const float* dock = (const float*)d_in[0];
    const float* grid = (const float*)d_in[1];
    const float* Wq   = (const float*)d_in[2];
    const float* bq   = (const float*)d_in[3];
    const float* Wk   = (const float*)d_in[4];
    // d_in[5] = bk: q.bk is constant over spatial axis -> cancels in softmax; unused
    const float* Wv   = (const float*)d_in[6];
    const float* bv   = (const float*)d_in[7];
    const float* Wo   = (const float*)d_in[8];
    const float* bo   = (const float*)d_in[9];
    float* out = (float*)d_out;
    float* ws  = (float*)d_ws;

    precompute_kernel<<<1, 256, 0, stream>>>(Wq, bq, Wk, Wv, bv, Wo, bo, ws);

    const int b_total = in_sizes[0] / 75;   // 65536
    const int blocks = (b_total + NW - 1) / NW;
    dock_attn_kernel<<<blocks, 256, 0, stream>>>(dock, grid, ws, out, b_total);
}